// Round 4
// 45737.808 us; speedup vs baseline: 2.6113x; 2.6113x over previous
//
#include <hip/hip_runtime.h>
#include <cstdio>

typedef __attribute__((ext_vector_type(8))) short bf16x8;
typedef __attribute__((ext_vector_type(4))) float f32x4;
typedef unsigned short u16;

__device__ __forceinline__ float bf2f(u16 h) {
    union { unsigned u; float f; } v; v.u = ((unsigned)h) << 16; return v.f;
}
__device__ __forceinline__ u16 f2bf(float f) {
    union { float f; unsigned u; } v; v.f = f;
    unsigned u = v.u;
    unsigned r = (u + 0x7fffu + ((u >> 16) & 1u)) >> 16;
    return (u16)r;
}
// split f32 -> hi+lo bf16 (a ~= hi+lo, rel err ~2^-17)
__device__ __forceinline__ void split8(const float* p, uint4& hi, uint4& lo) {
    float a[8];
    *(float4*)&a[0] = *(const float4*)p;
    *(float4*)&a[4] = *(const float4*)(p + 4);
    u16 h[8], l[8];
#pragma unroll
    for (int i = 0; i < 8; i++) {
        u16 hb = f2bf(a[i]);
        h[i] = hb;
        l[i] = f2bf(a[i] - bf2f(hb));
    }
    hi = (uint4){(unsigned)h[0] | ((unsigned)h[1] << 16), (unsigned)h[2] | ((unsigned)h[3] << 16),
                 (unsigned)h[4] | ((unsigned)h[5] << 16), (unsigned)h[6] | ((unsigned)h[7] << 16)};
    lo = (uint4){(unsigned)l[0] | ((unsigned)l[1] << 16), (unsigned)l[2] | ((unsigned)l[3] << 16),
                 (unsigned)l[4] | ((unsigned)l[5] << 16), (unsigned)l[6] | ((unsigned)l[7] << 16)};
}
__device__ __forceinline__ float gelu_exact(float x) {
    return 0.5f * x * (1.0f + erff(x * 0.70710678118654752f));
}
__device__ __forceinline__ float cvt(const void* p, size_t i, unsigned f) {
    return f ? bf2f(((const u16*)p)[i]) : ((const float*)p)[i];
}

// ---------------------------------------------------------------------------
// Dtype probe (kept as a guard; inputs confirmed f32 on this harness).
// ---------------------------------------------------------------------------
__global__ void detect_dt(const unsigned* ln1w, unsigned* flag)
{
    if (threadIdx.x == 0 && blockIdx.x == 0)
        flag[0] = (ln1w[0] == 0x3F803F80u) ? 1u : 0u;
}

// ---------------------------------------------------------------------------
// Canonicalizers (flag-driven; uniform branch).
// ---------------------------------------------------------------------------
__global__ void k_canon_split(const void* __restrict__ src, u16* __restrict__ hi,
                              u16* __restrict__ lo, int n, const unsigned* flag)
{
    unsigned f = flag[0];
    for (int i = blockIdx.x * blockDim.x + threadIdx.x; i < n; i += gridDim.x * blockDim.x) {
        if (f) { hi[i] = ((const u16*)src)[i]; lo[i] = 0; }
        else {
            float v = ((const float*)src)[i];
            u16 h = f2bf(v);
            hi[i] = h;
            lo[i] = f2bf(v - bf2f(h));
        }
    }
}
__global__ void k_canon_f32(const void* __restrict__ src, float* __restrict__ dst,
                            int n, const unsigned* flag)
{
    unsigned f = flag[0];
    for (int i = blockIdx.x * blockDim.x + threadIdx.x; i < n; i += gridDim.x * blockDim.x)
        dst[i] = cvt(src, i, f);
}
__global__ void k_canon_sum(const void* __restrict__ a, const void* __restrict__ b,
                            float* __restrict__ dst, int n, const unsigned* flag)
{
    unsigned f = flag[0];
    for (int i = blockIdx.x * blockDim.x + threadIdx.x; i < n; i += gridDim.x * blockDim.x)
        dst[i] = cvt(a, i, f) + cvt(b, i, f);
}

// ---------------------------------------------------------------------------
// Split-precision B^T GEMM. C[m][n] = act(sum_k A[m][k]*W[n][k] + bias[n]).
// 128x128 tile, BK=32 (LDS 32 KiB), 4 waves 2x2, XOR-swizzled LDS, 3-term
// split-bf16 MFMA (hh + hl + lh) -> ~f32 precision.
// AF32=1: Ah_ is f32 (in-kernel split). AF32=0: Ah_/Al_ pre-split bf16.
// W pre-split bf16 hi/lo. SWAP: out row m=b*512+t -> t*32+b. OF32: f32/bf16 out.
// ---------------------------------------------------------------------------
template <int SWAP, int GELU, int AF32, int OF32>
__global__ __launch_bounds__(256) void gemm_bt(
    const void* __restrict__ Ah_, const void* __restrict__ Al_,
    const u16* __restrict__ Wh, const u16* __restrict__ Wl,
    const float* __restrict__ bias, void* __restrict__ C,
    int M, int N, int K)
{
    __shared__ __align__(16) u16 AhS[128 * 32];
    __shared__ __align__(16) u16 AlS[128 * 32];
    __shared__ __align__(16) u16 BhS[128 * 32];
    __shared__ __align__(16) u16 BlS[128 * 32];
    const int tid  = threadIdx.x;
    const int lane = tid & 63;
    const int wave = tid >> 6;
    const int wm = wave >> 1, wn = wave & 1;
    const int bn = blockIdx.x, bm = blockIdx.y;
    const int q = lane >> 4, ln16 = lane & 15;

    f32x4 acc[4][4];
#pragma unroll
    for (int i = 0; i < 4; i++)
#pragma unroll
        for (int j = 0; j < 4; j++) acc[i][j] = (f32x4){0.f, 0.f, 0.f, 0.f};

    const size_t arow0 = (size_t)bm * 128;
    const size_t brow0 = (size_t)bn * 128;

    for (int k0 = 0; k0 < K; k0 += 32) {
        __syncthreads();
#pragma unroll
        for (int c = 0; c < 2; c++) {
            int f  = c * 256 + tid;      // 0..511
            int r  = f >> 2;             // row 0..127
            int ch = f & 3;              // 8-elem chunk 0..3
            int off = r * 32 + ((ch ^ (r & 3)) * 8);
            if (AF32) {
                uint4 hi, lo;
                split8((const float*)Ah_ + (arow0 + r) * K + k0 + ch * 8, hi, lo);
                *(uint4*)(&AhS[off]) = hi;
                *(uint4*)(&AlS[off]) = lo;
            } else {
                *(uint4*)(&AhS[off]) = *(const uint4*)((const u16*)Ah_ + (arow0 + r) * K + k0 + ch * 8);
                *(uint4*)(&AlS[off]) = *(const uint4*)((const u16*)Al_ + (arow0 + r) * K + k0 + ch * 8);
            }
            *(uint4*)(&BhS[off]) = *(const uint4*)(Wh + (brow0 + r) * K + k0 + ch * 8);
            *(uint4*)(&BlS[off]) = *(const uint4*)(Wl + (brow0 + r) * K + k0 + ch * 8);
        }
        __syncthreads();
        bf16x8 afh[4], afl[4], bfh[4], bfl[4];
#pragma unroll
        for (int i = 0; i < 4; i++) {
            int row = wm * 64 + i * 16 + ln16;
            int o = row * 32 + ((q ^ (row & 3)) * 8);
            afh[i] = *(const bf16x8*)(&AhS[o]);
            afl[i] = *(const bf16x8*)(&AlS[o]);
        }
#pragma unroll
        for (int j = 0; j < 4; j++) {
            int row = wn * 64 + j * 16 + ln16;
            int o = row * 32 + ((q ^ (row & 3)) * 8);
            bfh[j] = *(const bf16x8*)(&BhS[o]);
            bfl[j] = *(const bf16x8*)(&BlS[o]);
        }
#pragma unroll
        for (int i = 0; i < 4; i++)
#pragma unroll
            for (int j = 0; j < 4; j++) {
                acc[i][j] = __builtin_amdgcn_mfma_f32_16x16x32_bf16(afh[i], bfh[j], acc[i][j], 0, 0, 0);
                acc[i][j] = __builtin_amdgcn_mfma_f32_16x16x32_bf16(afh[i], bfl[j], acc[i][j], 0, 0, 0);
                acc[i][j] = __builtin_amdgcn_mfma_f32_16x16x32_bf16(afl[i], bfh[j], acc[i][j], 0, 0, 0);
            }
    }

    // epilogue: C layout col=lane&15, row=(lane>>4)*4+reg (m89-verified)
#pragma unroll
    for (int j = 0; j < 4; j++) {
        int n = bn * 128 + wn * 64 + j * 16 + ln16;
        float bs = bias[n];
#pragma unroll
        for (int i = 0; i < 4; i++) {
#pragma unroll
            for (int r = 0; r < 4; r++) {
                int m = bm * 128 + wm * 64 + i * 16 + q * 4 + r;
                float v = acc[i][j][r] + bs;
                if (GELU) v = gelu_exact(v);
                int orow = SWAP ? (((m & 511) << 5) | (m >> 9)) : m;
                if (OF32) ((float*)C)[(size_t)orow * N + n] = v;
                else      ((u16*)C)[(size_t)orow * N + n] = f2bf(v);
            }
        }
    }
}

// ---------------------------------------------------------------------------
// Per-timestep LSTM kernel (NO cooperative launch). One launch per t; the
// inter-step barrier is stream ordering -> no grid.sync, no co-residency
// validation, no XCD coherence concerns. c-state lives in cbuf[32][1024]
// (unique per-thread ownership, read t-1 / write t in the same kernel).
//
// Rounds 1-3 failed with BIT-IDENTICAL output across three different
// cooperative-kernel bodies => the rewritten lstm_coop never executed
// (silent coop-launch rejection or stale artifact). This removes the
// unverifiable dependency entirely.
//
// Tiling (reuse-heavy, fixes baseline's 16x W reload / VGPR=56 load-sink):
//  * block (nb 0..255, bg 0..1): cols nb*4..+3, batches bg*16..+15.
//  * wave = gate q; lane = bq*16+kq; thread tile = 4 gate-rows x 4
//    batches x 64 k (k-slice kq*64..+63).
//  * W float4 loaded once per i-iter, reused across 4 batches in regs;
//    4 same-address lanes merge in the coalescer -> ~64 KB unique
//    W/block/step from L2/L3 (baseline: ~1 MB effective).
//  * h float4: rows bq*4+bb, chunk kq -> 64 distinct 16B segs/instr,
//    coalesced; 4x wave duplication served by L1. ~64 KB unique/block.
//  * 16-lane shfl_xor reduce -> red[16][16] -> gate phase (tid<64),
//    identical math to the passing baseline.
// ---------------------------------------------------------------------------
__global__ __launch_bounds__(256) void lstm_step(
    const u16* __restrict__ xg, const float* __restrict__ Whh,
    float* __restrict__ hout, float* __restrict__ cbuf, int t)
{
    __shared__ float red[16][16];
    const int tid = threadIdx.x;
    const int nb = blockIdx.x & 255;   // 4-column group of H
    const int bg = blockIdx.x >> 8;    // batch half (16 b each)
    const int q    = tid >> 6;         // wave id = gate 0..3 (i,f,g,o)
    const int lane = tid & 63;
    const int bq = lane >> 4;          // batch quartet 0..3
    const int kq = lane & 15;          // 64-float k-chunk 0..15

    if (t > 0) {
        // W rows (q*1024 + nb*4 + j), j=0..3; k-slice kq*64..+63
        const float* wp = Whh + ((size_t)(q * 1024 + nb * 4)) * 1024 + kq * 64;
        const float* hsrc = hout + ((size_t)(t - 1) * 32 + bg * 16) * 1024 + kq * 64;

        float p[4][4];
#pragma unroll
        for (int j = 0; j < 4; j++)
#pragma unroll
            for (int bb = 0; bb < 4; bb++) p[j][bb] = 0.f;

#pragma unroll
        for (int i = 0; i < 16; i++) {
            float4 wj0 = *(const float4*)(wp + i * 4);
            float4 wj1 = *(const float4*)(wp + 1024 + i * 4);
            float4 wj2 = *(const float4*)(wp + 2048 + i * 4);
            float4 wj3 = *(const float4*)(wp + 3072 + i * 4);
#pragma unroll
            for (int bb = 0; bb < 4; bb++) {
                float4 hv = *(const float4*)(hsrc + (size_t)(bq * 4 + bb) * 1024 + i * 4);
                p[0][bb] += wj0.x * hv.x + wj0.y * hv.y + wj0.z * hv.z + wj0.w * hv.w;
                p[1][bb] += wj1.x * hv.x + wj1.y * hv.y + wj1.z * hv.z + wj1.w * hv.w;
                p[2][bb] += wj2.x * hv.x + wj2.y * hv.y + wj2.z * hv.z + wj2.w * hv.w;
                p[3][bb] += wj3.x * hv.x + wj3.y * hv.y + wj3.z * hv.z + wj3.w * hv.w;
            }
        }

        // reduce over the 16 kq lanes (width-16 segments share bq)
#pragma unroll
        for (int j = 0; j < 4; j++)
#pragma unroll
            for (int bb = 0; bb < 4; bb++) {
                float s = p[j][bb];
                s += __shfl_xor(s, 8, 16);
                s += __shfl_xor(s, 4, 16);
                s += __shfl_xor(s, 2, 16);
                s += __shfl_xor(s, 1, 16);
                if (kq == 0) red[q * 4 + j][bq * 4 + bb] = s;
            }
    }
    __syncthreads();
    if (tid < 64) {
        const int ub = tid >> 2, uj = tid & 3;
        float G[4];
#pragma unroll
        for (int gg = 0; gg < 4; gg++) {
            size_t xi = ((size_t)t * 32 + bg * 16 + ub) * 4096 + gg * 1024 + nb * 4 + uj;
            G[gg] = bf2f(xg[xi]) + ((t > 0) ? red[gg * 4 + uj][ub] : 0.f);
        }
        const size_t ci = (size_t)(bg * 16 + ub) * 1024 + nb * 4 + uj;
        float c_state = (t > 0) ? cbuf[ci] : 0.f;
        float ig = 1.f / (1.f + __expf(-G[0]));
        float fg = 1.f / (1.f + __expf(-G[1]));
        float gv = tanhf(G[2]);
        float og = 1.f / (1.f + __expf(-G[3]));
        c_state = fg * c_state + ig * gv;
        float h = og * tanhf(c_state);
        cbuf[ci] = c_state;
        hout[((size_t)t * 32 + bg * 16 + ub) * 1024 + nb * 4 + uj] = h;
    }
}

// ---------------------------------------------------------------------------
// Row LayerNorm (+ optional exact GELU), f32 math. One block per 1024-row.
// SWAPOUT: row m = t*32+b -> out row b*512+t.
// ---------------------------------------------------------------------------
template <int GELU, int SWAPOUT, int OUTF32>
__global__ __launch_bounds__(256) void ln_act(
    const float* __restrict__ in, const float* __restrict__ w,
    const float* __restrict__ b, void* __restrict__ out)
{
    const int m = blockIdx.x, tid = threadIdx.x, lane = tid & 63, wave = tid >> 6;
    float4 t4 = ((const float4*)(in + (size_t)m * 1024))[tid];
    float v[4] = {t4.x, t4.y, t4.z, t4.w};
    float s  = v[0] + v[1] + v[2] + v[3];
    float qs = v[0] * v[0] + v[1] * v[1] + v[2] * v[2] + v[3] * v[3];
#pragma unroll
    for (int off = 32; off > 0; off >>= 1) {
        s  += __shfl_down(s, off);
        qs += __shfl_down(qs, off);
    }
    __shared__ float ssm[4], qsm[4];
    if (lane == 0) { ssm[wave] = s; qsm[wave] = qs; }
    __syncthreads();
    float S = ssm[0] + ssm[1] + ssm[2] + ssm[3];
    float Q = qsm[0] + qsm[1] + qsm[2] + qsm[3];
    float mean = S * (1.f / 1024.f);
    float var  = Q * (1.f / 1024.f) - mean * mean;
    float rstd = rsqrtf(fmaxf(var, 0.f) + 1e-5f);
    int orow = SWAPOUT ? (((m & 31) << 9) | (m >> 5)) : m;
    float o[4];
#pragma unroll
    for (int e = 0; e < 4; e++) {
        float f = (v[e] - mean) * rstd * w[tid * 4 + e] + b[tid * 4 + e];
        if (GELU) f = gelu_exact(f);
        o[e] = f;
    }
    if (OUTF32) {
        ((float4*)((float*)out + (size_t)orow * 1024))[tid] = (float4){o[0], o[1], o[2], o[3]};
    } else {
        ushort4 po = { f2bf(o[0]), f2bf(o[1]), f2bf(o[2]), f2bf(o[3]) };
        *(ushort4*)((u16*)out + (size_t)orow * 1024 + tid * 4) = po;
    }
}

// ---------------------------------------------------------------------------
// ws layout (256 MiB): flag 4K | persistent canon ~52.2Mi (incl cbuf 128K) |
// h-region 64Mi (first 20Mi shared with x/Wih0 canon, dead after gemm0) |
// xg bf16 128Mi (y f32 / y2 f32 reuse after recurrences). d_out written ONLY
// by final LN, as FLOAT32 (the reference's output dtype).
// ---------------------------------------------------------------------------
extern "C" void kernel_launch(void* const* d_in, const int* in_sizes, int n_in,
                              void* d_out, int out_size, void* d_ws, size_t ws_size,
                              hipStream_t stream)
{
    const int M = 16384;
    const void* x    = d_in[0];
    const void* Wih0 = d_in[1];
    const void* Whh0 = d_in[2];
    const void* bih0 = d_in[3];
    const void* bhh0 = d_in[4];
    const void* Wih1 = d_in[5];
    const void* Whh1 = d_in[6];
    const void* bih1 = d_in[7];
    const void* bhh1 = d_in[8];
    const void* ln1w = d_in[9];
    const void* ln1b = d_in[10];
    const void* linw = d_in[11];
    const void* linb = d_in[12];
    const void* ln2w = d_in[13];
    const void* ln2b = d_in[14];
    float* outp = (float*)d_out;   // reference output dtype = float32

    char* p = (char*)d_ws;
    unsigned* flag = (unsigned*)p;              p += 4096;
    float* whh0f = (float*)p;                   p += (size_t)4096 * 1024 * 4;   // 16Mi
    float* whh1f = (float*)p;                   p += (size_t)4096 * 1024 * 4;   // 16Mi
    u16* wih1h = (u16*)p;                       p += (size_t)4096 * 1024 * 2;   // 8Mi
    u16* wih1l = (u16*)p;                       p += (size_t)4096 * 1024 * 2;   // 8Mi
    u16* linwh = (u16*)p;                       p += (size_t)1024 * 1024 * 2;   // 2Mi
    u16* linwl = (u16*)p;                       p += (size_t)1024 * 1024 * 2;   // 2Mi
    float* cbuf  = (float*)p;                   p += (size_t)32 * 1024 * 4;     // 128Ki
    float* bsum0 = (float*)p;                   p += 4096 * 4;
    float* bsum1 = (float*)p;                   p += 4096 * 4;
    float* linbf = (float*)p;                   p += 1024 * 4;
    float* ln1wf = (float*)p;                   p += 1024 * 4;
    float* ln1bf = (float*)p;                   p += 1024 * 4;
    float* ln2wf = (float*)p;                   p += 1024 * 4;
    float* ln2bf = (float*)p;                   p += 1024 * 4;
    p = (char*)(((size_t)p + 255) & ~(size_t)255);
    char* hbase = p;
    u16* xh    = (u16*)p;                       p += (size_t)M * 256 * 2;       // 8Mi
    u16* xl    = (u16*)p;                       p += (size_t)M * 256 * 2;       // 8Mi
    u16* wih0h = (u16*)p;                       p += (size_t)4096 * 256 * 2;    // 2Mi
    u16* wih0l = (u16*)p;                       p += (size_t)4096 * 256 * 2;    // 2Mi
    float* hbuf = (float*)hbase;                // [T][32][1024] f32 = 64Mi
    p = hbase + (size_t)M * 1024 * 4;
    u16* xg   = (u16*)p;                        // 128Mi
    float* y  = (float*)p;
    float* y2 = (float*)(p + (size_t)M * 1024 * 4);

    // 1) dtype probe -> flag
    hipLaunchKernelGGL(detect_dt, dim3(1), dim3(64), 0, stream, (const unsigned*)ln1w, flag);
    // 2) canonicalize
    hipLaunchKernelGGL(k_canon_split, dim3(1024), dim3(256), 0, stream, x, xh, xl, M * 256, flag);
    hipLaunchKernelGGL(k_canon_split, dim3(512), dim3(256), 0, stream, Wih0, wih0h, wih0l, 4096 * 256, flag);
    hipLaunchKernelGGL(k_canon_split, dim3(1024), dim3(256), 0, stream, Wih1, wih1h, wih1l, 4096 * 1024, flag);
    hipLaunchKernelGGL(k_canon_split, dim3(512), dim3(256), 0, stream, linw, linwh, linwl, 1024 * 1024, flag);
    hipLaunchKernelGGL(k_canon_f32, dim3(1024), dim3(256), 0, stream, Whh0, whh0f, 4096 * 1024, flag);
    hipLaunchKernelGGL(k_canon_f32, dim3(1024), dim3(256), 0, stream, Whh1, whh1f, 4096 * 1024, flag);
    hipLaunchKernelGGL(k_canon_sum, dim3(16), dim3(256), 0, stream, bih0, bhh0, bsum0, 4096, flag);
    hipLaunchKernelGGL(k_canon_sum, dim3(16), dim3(256), 0, stream, bih1, bhh1, bsum1, 4096, flag);
    hipLaunchKernelGGL(k_canon_f32, dim3(4), dim3(256), 0, stream, linb, linbf, 1024, flag);
    hipLaunchKernelGGL(k_canon_f32, dim3(4), dim3(256), 0, stream, ln1w, ln1wf, 1024, flag);
    hipLaunchKernelGGL(k_canon_f32, dim3(4), dim3(256), 0, stream, ln1b, ln1bf, 1024, flag);
    hipLaunchKernelGGL(k_canon_f32, dim3(4), dim3(256), 0, stream, ln2w, ln2wf, 1024, flag);
    hipLaunchKernelGGL(k_canon_f32, dim3(4), dim3(256), 0, stream, ln2b, ln2bf, 1024, flag);

    // 3) xg0 = x @ Wih0^T + bsum0  (rows b*512+t -> t*32+b)
    hipLaunchKernelGGL((gemm_bt<1, 0, 0, 0>), dim3(32, 128), dim3(256), 0, stream,
                       (const void*)xh, (const void*)xl, wih0h, wih0l, bsum0,
                       (void*)xg, M, 4096, 256);
    // 4) layer-0 recurrence: one kernel per timestep (stream-ordered barrier)
    for (int t = 0; t < 512; t++)
        hipLaunchKernelGGL(lstm_step, dim3(512), dim3(256), 0, stream,
                           (const u16*)xg, (const float*)whh0f, hbuf, cbuf, t);
    // 5) xg1 = h0 @ Wih1^T + bsum1 (A f32, in-kernel split)
    hipLaunchKernelGGL((gemm_bt<0, 0, 1, 0>), dim3(32, 128), dim3(256), 0, stream,
                       (const void*)hbuf, (const void*)0, wih1h, wih1l, bsum1,
                       (void*)xg, M, 4096, 1024);
    // 6) layer-1 recurrence (h in place; cbuf reset via t==0 path)
    for (int t = 0; t < 512; t++)
        hipLaunchKernelGGL(lstm_step, dim3(512), dim3(256), 0, stream,
                           (const u16*)xg, (const float*)whh1f, hbuf, cbuf, t);
    // 7) LN1 + GELU: h f32 -> y f32 (xg region, xg dead)
    hipLaunchKernelGGL((ln_act<1, 0, 1>), dim3(M), dim3(256), 0, stream,
                       hbuf, ln1wf, ln1bf, (void*)y);
    // 8) lin + GELU: y2 = gelu(y @ linw^T + linb)  (f32 out)
    hipLaunchKernelGGL((gemm_bt<0, 1, 1, 1>), dim3(8, 128), dim3(256), 0, stream,
                       (const void*)y, (const void*)0, linwh, linwl, linbf,
                       (void*)y2, M, 1024, 1024);
    // 9) LN2 -> d_out as FLOAT32, rows t*32+b -> b*512+t
    hipLaunchKernelGGL((ln_act<0, 1, 1>), dim3(M), dim3(256), 0, stream,
                       y2, ln2wf, ln2bf, (void*)outp);
}